// Round 4
// baseline (204.281 us; speedup 1.0000x reference)
//
#include <hip/hip_runtime.h>
#include <cmath>

// ---------------- problem constants ----------------
#define M_ROWS   11520      // 2*5760
#define DIM      512
#define HID      1960
#define HIDP     2048       // padded HID (zeros)
#define KP2      1984       // GEMM2 K-loop bound: 31*64 >= HID, cols [1960,1984) are zero
#define OH       20
#define OW       36
#define LVEC     720        // OH*OW
#define NCH      40         // HID/49
#define BPRIME   16         // M_ROWS / LVEC
#define HP       66         // 60 + 2*3
#define WP       114        // 108 + 2*3

typedef unsigned short u16;
typedef __bf16 bf16x8 __attribute__((ext_vector_type(8)));
typedef float  f32x4  __attribute__((ext_vector_type(4)));
typedef unsigned short u16x8 __attribute__((ext_vector_type(8)));

__device__ __forceinline__ u16 f2bf(float f) {
    unsigned u = __float_as_uint(f);
    u += 0x7fffu + ((u >> 16) & 1u);   // RNE
    return (u16)(u >> 16);
}
__device__ __forceinline__ float bf2f(u16 h) {
    return __uint_as_float(((unsigned)h) << 16);
}

__device__ __forceinline__ void gload_lds16(const void* g, void* l) {
    __builtin_amdgcn_global_load_lds(
        (const __attribute__((address_space(1))) void*)g,
        (__attribute__((address_space(3))) void*)l, 16, 0, 0);
}

// Raw barrier with compiler-level memory fences (no implicit vmcnt(0) drain,
// unlike __syncthreads). HW-level waits are issued explicitly via asm.
__device__ __forceinline__ void wg_barrier() {
    asm volatile("" ::: "memory");
    __builtin_amdgcn_s_barrier();
    asm volatile("" ::: "memory");
}

// ---------------- fused fp32 -> bf16 converts + g2 pad-zeroing (one dispatch) ----------------
#define CVT_XB   5760
#define CVT_W1B  1024
#define CVT_W2B  1024
#define CVT_Z    270       // 11520 rows * 24 cols / (256*4)
__global__ __launch_bounds__(256) void cvt_all(const float* __restrict__ x,
                                               const float* __restrict__ W1,
                                               const float* __restrict__ W2,
                                               u16* __restrict__ xb,
                                               u16* __restrict__ W1b,
                                               u16* __restrict__ W2b,
                                               u16* __restrict__ g2) {
    const int b = blockIdx.x;
    const int tid = threadIdx.x;
    ushort4 o;
    if (b < CVT_XB) {
        int i = (b * 256 + tid) * 4;
        float4 v = *(const float4*)(x + i);
        o.x = f2bf(v.x); o.y = f2bf(v.y); o.z = f2bf(v.z); o.w = f2bf(v.w);
        *(ushort4*)(xb + i) = o;
    } else if (b < CVT_XB + CVT_W1B) {
        int i = ((b - CVT_XB) * 256 + tid) * 4;      // over 2048*512
        if (i < HID * DIM) {
            float4 v = *(const float4*)(W1 + i);
            o.x = f2bf(v.x); o.y = f2bf(v.y); o.z = f2bf(v.z); o.w = f2bf(v.w);
        } else {
            o.x = o.y = o.z = o.w = 0;
        }
        *(ushort4*)(W1b + i) = o;
    } else if (b < CVT_XB + CVT_W1B + CVT_W2B) {
        int i = ((b - CVT_XB - CVT_W1B) * 256 + tid) * 4;   // over 512*2048
        int d = i / HIDP, c = i - d * HIDP;
        if (c < HID) {
            float4 v = *(const float4*)(W2 + (size_t)d * HID + c);
            o.x = f2bf(v.x); o.y = f2bf(v.y); o.z = f2bf(v.z); o.w = f2bf(v.w);
        } else {
            o.x = o.y = o.z = o.w = 0;
        }
        *(ushort4*)(W2b + i) = o;
    } else {
        int i = ((b - CVT_XB - CVT_W1B - CVT_W2B) * 256 + tid) * 4;  // over 11520*24
        int row = i / 24, c = i - row * 24;
        o.x = o.y = o.z = o.w = 0;
        *(ushort4*)(g2 + (size_t)row * HIDP + HID + c) = o;
    }
}

// ---------------- bf16 NT-GEMM, ring-3 software pipeline (counted vmcnt) ----------------
// C[m,n] = sum_k A[m,k]*B[n,k] + bias[n].  BM x BN tile, BK K-step,
// 512 threads = 8 waves (4M x 2N), wave tile (BM/4)x(BN/2), mfma 16x16x32.
//
// Pipeline: 3 LDS buffers; iteration t:
//   { issue tile t+2 -> buf[(t+2)%3];  s_waitcnt vmcnt(6);  barrier;
//     ds_read frags(buf[t%3]);  MFMA;  barrier }
// Invariant: after the issue, outstanding per-thread loads = tiles {t,t+1,t+2}
// = 9; vmcnt(6) drains exactly tile t's 3 loads (FIFO per wave) before any
// read of buf[t%3].  Two full tiles stay in flight across BOTH barriers, so
// the per-step HBM latency drain of the old 2-barrier structure disappears.
// Race-freedom of the prefetch: buf[(t+2)%3] was last read in iteration t-1,
// and every wave's issue in iteration t is program-ordered after the trailing
// barrier of t-1, which all waves reached only after finishing those reads.
// Tail (nothing issued): t=NT-2 -> vmcnt(3), t=NT-1 -> vmcnt(0).
// Requires exactly 3 gloads/thread/tile: (BM+BN)*BK/8 == 3*512.
//
// LDS XOR swizzle (both-sides): global chunk cg = cp ^ key(row), frag read
// slot c = (kk*4+quad) ^ key(row); key = row&7 (BK=64, 8 chunks/row) or
// (row>>1)&3 (BK=32, 4 chunks/row) -- both give a perfectly bank-balanced
// ds_read_b128 (every bank exactly 8 words per wave access).
//
// XCD swizzle as before (grid % 8 == 0).
template <int OUT_BF16, int BM, int BN, int BK>
__global__ __launch_bounds__(512, 4) void gemm_ring(const u16* __restrict__ A,
                                                    const u16* __restrict__ B,
                                                    const float* __restrict__ bias,
                                                    int biasN, void* __restrict__ Cout,
                                                    int N, int K, int ldk) {
    constexpr int WM  = BM / 4;
    constexpr int WN  = BN / 2;
    constexpr int MU  = WM / 16;
    constexpr int NU  = WN / 16;
    constexpr int KB  = BK / 32;          // mfma K=32 steps per K-tile
    constexpr int CPR = BK / 8;           // 16B chunks per row
    constexpr int CA  = BM * CPR;         // A-tile chunks
    constexpr int CB  = BN * CPR;         // B-tile chunks
    constexpr int TILEU = (BM + BN) * BK; // u16 per (A+B) tile
    static_assert(CA % 512 == 0 && CB % 512 == 0, "chunk split");
    static_assert(CA / 512 + CB / 512 == 3, "need 3 loads/thread for vmcnt(6/3/0)");

    __shared__ u16 smem[3 * TILEU];       // 72 KB for both instantiations

    const int tid  = threadIdx.x;
    const int ntn  = N / BN;
    const int NB   = gridDim.x;
    const int v    = (blockIdx.x & 7) * (NB >> 3) + (blockIdx.x >> 3);
    const int bm   = v / ntn;
    const int bn   = v - bm * ntn;
    const int lane = tid & 63;
    const int wv   = tid >> 6;
    const int wm   = (wv >> 1) * WM;
    const int wn   = (wv & 1) * WN;
    const int r    = lane & 15;
    const int quad = lane >> 4;

    const size_t Arow0 = (size_t)bm * BM * ldk;
    const size_t Brow0 = (size_t)bn * BN * ldk;
    const int NT = K / BK;

    auto issue = [&](int t) {
        const size_t kt = (size_t)t * BK;
        u16* sa = smem + (t % 3) * TILEU;
        u16* sb = sa + BM * BK;
#pragma unroll
        for (int i = 0; i < CA / 512; i++) {
            int e   = i * 512 + tid;
            int row = e / CPR;
            int cp  = e % CPR;
            int key = (BK == 64) ? (row & 7) : ((row >> 1) & 3);
            gload_lds16(A + Arow0 + (size_t)row * ldk + kt + (size_t)((cp ^ key) * 8),
                        (char*)sa + e * 16);
        }
#pragma unroll
        for (int i = 0; i < CB / 512; i++) {
            int e   = i * 512 + tid;
            int row = e / CPR;
            int cp  = e % CPR;
            int key = (BK == 64) ? (row & 7) : ((row >> 1) & 3);
            gload_lds16(B + Brow0 + (size_t)row * ldk + kt + (size_t)((cp ^ key) * 8),
                        (char*)sb + e * 16);
        }
    };

    issue(0);
    issue(1);

    f32x4 acc[MU][NU] = {};

    for (int t = 0; t < NT; ++t) {
        if (t + 2 < NT) issue(t + 2);
        if (t + 2 < NT)      asm volatile("s_waitcnt vmcnt(6)" ::: "memory");
        else if (t + 1 < NT) asm volatile("s_waitcnt vmcnt(3)" ::: "memory");
        else                 asm volatile("s_waitcnt vmcnt(0)" ::: "memory");
        wg_barrier();                       // tile t published to all waves

        const u16* sa = smem + (t % 3) * TILEU;
        const u16* sb = sa + BM * BK;
#pragma unroll
        for (int kk = 0; kk < KB; kk++) {
            bf16x8 af[MU], bg[NU];
#pragma unroll
            for (int m = 0; m < MU; m++) {
                int row = wm + m * 16 + r;
                int key = (BK == 64) ? (row & 7) : ((row >> 1) & 3);
                int c   = (kk * 4 + quad) ^ key;
                af[m] = *(const bf16x8*)(sa + row * BK + c * 8);
            }
#pragma unroll
            for (int u = 0; u < NU; u++) {
                int row = wn + u * 16 + r;
                int key = (BK == 64) ? (row & 7) : ((row >> 1) & 3);
                int c   = (kk * 4 + quad) ^ key;
                bg[u] = *(const bf16x8*)(sb + row * BK + c * 8);
            }
#pragma unroll
            for (int m = 0; m < MU; m++)
#pragma unroll
                for (int u = 0; u < NU; u++)
                    acc[m][u] = __builtin_amdgcn_mfma_f32_16x16x32_bf16(
                        af[m], bg[u], acc[m][u], 0, 0, 0);
        }
        wg_barrier();                       // reads(t) done -> buffer reusable
    }

    if constexpr (OUT_BF16) {
        // LDS-bounce epilogue: pack the C-tile (BM x BN bf16, padded stride
        // BN+8) into smem, then fully-coalesced 16B stores (fixes the 1.6x
        // partial-line write amplification of per-element u16 stores).
        constexpr int LDC = BN + 8;
        static_assert(BM * LDC <= 3 * TILEU, "bounce fits in ring LDS");
        static_assert(BM == 256 && BN == 128, "store split assumes 256x128");
        u16* sC = smem;
#pragma unroll
        for (int u = 0; u < NU; u++) {
            int gnl = wn + u * 16 + r;
            int gng = bn * BN + gnl;
            float bv = (gng < biasN) ? bias[gng] : 0.0f;
#pragma unroll
            for (int m = 0; m < MU; m++) {
                int gml = wm + m * 16 + quad * 4;
#pragma unroll
                for (int q = 0; q < 4; q++)
                    sC[(gml + q) * LDC + gnl] = f2bf(acc[m][u][q] + bv);
            }
        }
        wg_barrier();
        // 512 threads, 2 per row: thread -> (row, half), 8 x 16B each
        const int row  = tid >> 1;
        const int half = tid & 1;
        const size_t gb = (size_t)(bm * BM + row) * N + bn * BN + half * 64;
        const u16* src = sC + row * LDC + half * 64;
#pragma unroll
        for (int j = 0; j < 8; j++) {
            u16x8 w = *(const u16x8*)(src + j * 8);
            *(u16x8*)((u16*)Cout + gb + j * 8) = w;
        }
    } else {
        // fp32 epilogue: 16 lanes x 4B = 64B full-line stores already
        const int gm0 = bm * BM + wm;
        const int gn0 = bn * BN + wn;
#pragma unroll
        for (int u = 0; u < NU; u++) {
            int gn = gn0 + u * 16 + r;
            float bv = (gn < biasN) ? bias[gn] : 0.0f;
#pragma unroll
            for (int m = 0; m < MU; m++) {
                int gm = gm0 + m * 16 + quad * 4;
#pragma unroll
                for (int q = 0; q < 4; q++)
                    ((float*)Cout)[(size_t)(gm + q) * N + gn] = acc[m][u][q] + bv;
            }
        }
    }
}

// ---------------- mid: fold + normalize + crop + GELU + unfold, fully fused ----------------
// (unchanged -- it dropped below the visibility cutoff in round 1)
__global__ __launch_bounds__(512) void mid_fused(const u16* __restrict__ hg,
                                                 u16* __restrict__ g2) {
    __shared__ u16 sh[12 * 20 * 56];   // 13440 u16 = 26880 B
    __shared__ u16 sG[34 * 58];        //  1972 u16 =  3944 B

    const int b   = blockIdx.x;
    const int bp  = b / (NCH * 4);
    const int rr  = b - bp * (NCH * 4);
    const int ch  = rr >> 2;
    const int s   = (rr >> 1) & 1;
    const int xh  = rr & 1;
    const int o0  = s * 10;            // first owned oy
    const int lo  = s * 8;             // first loaded oy
    const int ox0 = xh * 16;           // first loaded ox
    const int n0  = bp * LVEC;
    const int c0  = ch * 49;
    const int c0f = c0 & ~7;           // 16B-aligned channel base
    const int koff = c0 & 7;           // 0..7 (koff + 49 <= 56)
    const int tid = threadIdx.x;

    // phase 0: 12 oy-rows x 20 ox-cols x 7 chunks of 16B, DMA'd to LDS.
    {
        const char* hb = (const char*)(hg + (size_t)(n0 + lo * 36 + ox0) * HIDP + c0f);
        for (int t = tid; t < 12 * 20 * 7; t += 512) {
            int r   = (int)(((unsigned)t * 74899u) >> 19);
            int c   = t - r * 7;
            int loy = (int)(((unsigned)r * 3277u) >> 16);
            int oxl = r - 20 * loy;
            gload_lds16(hb + (size_t)(loy * 36 + oxl) * (HIDP * 2) + c * 16,
                        (char*)sh + t * 16);
        }
    }
    __syncthreads();

    // phase 1: G rows [3*o0, 3*o0+34) x local px [0,58) -> sG
    const int pxl = tid & 63;
    const int rg  = tid >> 6;          // 0..7, wave-uniform
    if (pxl < 58) {
        const int  pxg  = pxl + 54 * xh;              // global px
        const bool pxin = (pxg >= 3) && (pxg <= 110);
        const int  kx0  = pxg % 3;
        int  ct[3];
        bool vx[3];
        int  cx = 0;
#pragma unroll
        for (int dx = 0; dx < 3; dx++) {
            int kx = kx0 + 3 * dx, rx = pxg - kx;
            bool ok = pxin && (kx <= 6) && (rx >= 0) && (rx <= 105);
            vx[dx] = ok;
            ct[dx] = ok ? ((rx / 3) - ox0) * 56 + kx : 0;
            cx += ok ? 1 : 0;
        }
        const float fcx = (cx == 3) ? (1.0f / 3.0f) : ((cx == 2) ? 0.5f : 1.0f);

        for (int pr = rg; pr < 34; pr += 8) {
            int py = 3 * o0 + pr;      // wave-uniform
            float val = 0.0f;
            if (pxin && py >= 3 && py <= 62) {
                int ky0 = py % 3;
                float sum = 0.0f;
                int cy = 0;
#pragma unroll
                for (int dy = 0; dy < 3; dy++) {
                    int ky = ky0 + 3 * dy, ry = py - ky;   // uniform
                    if (ky <= 6 && ry >= 0 && ry <= 57) {  // uniform branch
                        int rt = (ry / 3 - lo) * (20 * 56) + ky * 7 + koff;
                        cy++;
                        float v0 = bf2f(sh[rt + ct[0]]);
                        float v1 = bf2f(sh[rt + ct[1]]);
                        float v2 = bf2f(sh[rt + ct[2]]);
                        sum += vx[0] ? v0 : 0.0f;
                        sum += vx[1] ? v1 : 0.0f;
                        sum += vx[2] ? v2 : 0.0f;
                    }
                }
                float fcy = (cy == 3) ? (1.0f / 3.0f) : ((cy == 2) ? 0.5f : 1.0f);
                float m = sum * fcx * fcy;
                val = 0.5f * m * (1.0f + erff(m * 0.70710678118654752f));  // exact gelu
            }
            sG[pr * 58 + pxl] = f2bf(val);
        }
    }
    __syncthreads();

    // phase 2: unfold sG -> g2 (magic-mul indices, no LUTs)
    {
        u16* g2row = g2 + (size_t)(n0 + o0 * 36 + 18 * xh) * HIDP + c0;
        for (int j = tid; j < 10 * 18 * 49; j += 512) {
            int l2 = (int)(((unsigned)j * 42800u) >> 21);
            int k  = j - l2 * 49;
            int oy = (int)(((unsigned)l2 * 57u) >> 10);
            int ox = l2 - 18 * oy;
            int ky = (int)(((unsigned)k * 37u) >> 8);
            int kx = k - 7 * ky;
            g2row[(size_t)(oy * 36 + ox) * HIDP + k] =
                sG[(3 * oy + ky) * 58 + 3 * ox + kx];
        }
    }
}

// ---------------- launch ----------------
extern "C" void kernel_launch(void* const* d_in, const int* in_sizes, int n_in,
                              void* d_out, int out_size, void* d_ws, size_t ws_size,
                              hipStream_t stream) {
    (void)in_sizes; (void)n_in; (void)out_size; (void)ws_size;
    const float* x  = (const float*)d_in[0];
    const float* W1 = (const float*)d_in[1];
    const float* b1 = (const float*)d_in[2];
    const float* W2 = (const float*)d_in[3];
    const float* b2 = (const float*)d_in[4];
    float* out = (float*)d_out;

    char* ws = (char*)d_ws;
    u16* xb  = (u16*)(ws);                       // 11520*512*2  = 11,796,480
    u16* W1b = (u16*)(ws + 11796480);            // 2048*512*2   =  2,097,152
    u16* W2b = (u16*)(ws + 13893632);            // 512*2048*2   =  2,097,152
    u16* hg  = (u16*)(ws + 15990784);            // 11520*2048*2 = 47,185,920
    u16* g2  = (u16*)(ws + 63176704);            // 11520*2048*2 = 47,185,920 (total 110 MB)

    // converts + g2 pad-zeroing (single dispatch)
    cvt_all<<<CVT_XB + CVT_W1B + CVT_W2B + CVT_Z, 256, 0, stream>>>(
        x, W1, W2, xb, W1b, W2b, g2);

    // GEMM1: h = x @ W1^T + b1 -> bf16 (11520 x 2048).  Ring-3 pipeline,
    // 256x128 tile, BK=32 (NT=16), 72 KB LDS -> 2 blocks/CU, grid 45*16=720.
    gemm_ring<1, 256, 128, 32><<<(M_ROWS / 256) * (HIDP / 128), 512, 0, stream>>>(
        xb, W1b, b1, HID, (void*)hg, HIDP, DIM, DIM);

    // middle: fold/normalize/gelu/unfold fused, hg -> g2 (G stays in LDS)
    mid_fused<<<BPRIME * NCH * 4, 512, 0, stream>>>(hg, g2);

    // GEMM2: out = g2 @ W2^T + b2 -> fp32 (11520 x 512).  Ring-3 pipeline,
    // 128x64 tile, BK=64 (NT=31), 72 KB LDS -> 2 blocks/CU, grid 90*8=720.
    gemm_ring<0, 128, 64, 64><<<(M_ROWS / 128) * (DIM / 64), 512, 0, stream>>>(
        g2, W2b, b2, DIM, (void*)out, DIM, KP2, HIDP);
}

// Round 5
// 193.573 us; speedup vs baseline: 1.0553x; 1.0553x over previous
//
#include <hip/hip_runtime.h>
#include <cmath>

// ---------------- problem constants ----------------
#define M_ROWS   11520      // 2*5760
#define DIM      512
#define HID      1960
#define HIDP     2048       // padded HID (zeros)
#define KP2      1984       // GEMM2 K-loop bound: 31*64 >= HID, cols [1960,1984) are zero
#define OH       20
#define OW       36
#define LVEC     720        // OH*OW
#define NCH      40         // HID/49
#define BPRIME   16         // M_ROWS / LVEC

typedef unsigned short u16;
typedef __bf16 bf16x8 __attribute__((ext_vector_type(8)));
typedef float  f32x4  __attribute__((ext_vector_type(4)));
typedef unsigned short u16x8 __attribute__((ext_vector_type(8)));

__device__ __forceinline__ u16 f2bf(float f) {
    unsigned u = __float_as_uint(f);
    u += 0x7fffu + ((u >> 16) & 1u);   // RNE
    return (u16)(u >> 16);
}
__device__ __forceinline__ float bf2f(u16 h) {
    return __uint_as_float(((unsigned)h) << 16);
}

__device__ __forceinline__ void gload_lds16(const void* g, void* l) {
    __builtin_amdgcn_global_load_lds(
        (const __attribute__((address_space(1))) void*)g,
        (__attribute__((address_space(3))) void*)l, 16, 0, 0);
}

// ---------------- fused fp32 -> bf16 converts + g2 pad-zeroing (one dispatch) ----------------
#define CVT_XB   5760
#define CVT_W1B  1024
#define CVT_W2B  1024
#define CVT_Z    270       // 11520 rows * 24 cols / (256*4)
__global__ __launch_bounds__(256) void cvt_all(const float* __restrict__ x,
                                               const float* __restrict__ W1,
                                               const float* __restrict__ W2,
                                               u16* __restrict__ xb,
                                               u16* __restrict__ W1b,
                                               u16* __restrict__ W2b,
                                               u16* __restrict__ g2) {
    const int b = blockIdx.x;
    const int tid = threadIdx.x;
    ushort4 o;
    if (b < CVT_XB) {
        int i = (b * 256 + tid) * 4;
        float4 v = *(const float4*)(x + i);
        o.x = f2bf(v.x); o.y = f2bf(v.y); o.z = f2bf(v.z); o.w = f2bf(v.w);
        *(ushort4*)(xb + i) = o;
    } else if (b < CVT_XB + CVT_W1B) {
        int i = ((b - CVT_XB) * 256 + tid) * 4;      // over 2048*512
        if (i < HID * DIM) {
            float4 v = *(const float4*)(W1 + i);
            o.x = f2bf(v.x); o.y = f2bf(v.y); o.z = f2bf(v.z); o.w = f2bf(v.w);
        } else {
            o.x = o.y = o.z = o.w = 0;
        }
        *(ushort4*)(W1b + i) = o;
    } else if (b < CVT_XB + CVT_W1B + CVT_W2B) {
        int i = ((b - CVT_XB - CVT_W1B) * 256 + tid) * 4;   // over 512*2048
        int d = i / HIDP, c = i - d * HIDP;
        if (c < HID) {
            float4 v = *(const float4*)(W2 + (size_t)d * HID + c);
            o.x = f2bf(v.x); o.y = f2bf(v.y); o.z = f2bf(v.z); o.w = f2bf(v.w);
        } else {
            o.x = o.y = o.z = o.w = 0;
        }
        *(ushort4*)(W2b + i) = o;
    } else {
        int i = ((b - CVT_XB - CVT_W1B - CVT_W2B) * 256 + tid) * 4;  // over 11520*24
        int row = i / 24, c = i - row * 24;
        o.x = o.y = o.z = o.w = 0;
        *(ushort4*)(g2 + (size_t)row * HIDP + HID + c) = o;
    }
}

// ---------------- GEMM1: h = x @ W1^T + b1 -> bf16 ----------------
// M=11520, K=512, N=2048 (cols >= 1960 zero).  128x128 tile, BK=64,
// 1024 threads = 16 waves (4M x 4N) of 32x32 each, acc[2][2] = 16 AGPR.
// __launch_bounds__(1024, 8): force unified regs <= 64 so 8 waves/SIMD ->
// 2 blocks/CU co-resident = 32 waves/CU (occupancy experiment: every prior
// config held >=92 regs -> 16 waves/CU and MfmaUtil pinned at ~19%).
// Structure: proven 2-barrier __syncthreads loop (ring reverted).
// Epilogue: LDS-bounce to 136-stride tile, 16B coalesced stores (round-4
// validated: WRITE_SIZE 75.5 -> 46 MB).
__global__ __launch_bounds__(1024, 8) void gemm1_k(const u16* __restrict__ A,
                                                   const u16* __restrict__ B,
                                                   const float* __restrict__ bias,
                                                   u16* __restrict__ C) {
    __shared__ u16 smem[128 * 136];      // 34,816 B; tile phase uses first 32 KB
    u16* sA = smem;                      // 128 x 64
    u16* sB = smem + 128 * 64;           // 128 x 64

    const int tid  = threadIdx.x;
    const int NB   = gridDim.x;          // 1440, %8==0
    const int v    = (blockIdx.x & 7) * (NB >> 3) + (blockIdx.x >> 3);
    const int bm   = v >> 4;             // ntn = 16
    const int bn   = v & 15;
    const int lane = tid & 63;
    const int wv   = tid >> 6;           // 0..15
    const int wm   = (wv >> 2) * 32;
    const int wn   = (wv & 3) * 32;
    const int r    = lane & 15;
    const int quad = lane >> 4;

    const size_t Arow0 = (size_t)bm * 128 * DIM;
    const size_t Brow0 = (size_t)bn * 128 * DIM;

    // per-thread staging slot (1 A chunk + 1 B chunk per K-step)
    const int srow = tid >> 3;
    const int scg  = (tid & 7) ^ (srow & 7);

    f32x4 acc[2][2] = {};

    for (int kt = 0; kt < DIM; kt += 64) {
        __syncthreads();
        gload_lds16(A + Arow0 + (size_t)srow * DIM + kt + scg * 8, (char*)sA + tid * 16);
        gload_lds16(B + Brow0 + (size_t)srow * DIM + kt + scg * 8, (char*)sB + tid * 16);
        __syncthreads();
#pragma unroll
        for (int kk = 0; kk < 2; kk++) {
            bf16x8 af[2], bg[2];
#pragma unroll
            for (int m = 0; m < 2; m++) {
                int row = wm + m * 16 + r;
                int c   = (kk * 4 + quad) ^ (row & 7);
                af[m] = *(const bf16x8*)(sA + row * 64 + c * 8);
            }
#pragma unroll
            for (int u = 0; u < 2; u++) {
                int row = wn + u * 16 + r;
                int c   = (kk * 4 + quad) ^ (row & 7);
                bg[u] = *(const bf16x8*)(sB + row * 64 + c * 8);
            }
#pragma unroll
            for (int m = 0; m < 2; m++)
#pragma unroll
                for (int u = 0; u < 2; u++)
                    acc[m][u] = __builtin_amdgcn_mfma_f32_16x16x32_bf16(
                        af[m], bg[u], acc[m][u], 0, 0, 0);
        }
    }

    // epilogue: bounce C-tile through LDS (stride 136), then 2x16B per thread
    __syncthreads();                     // all tile reads done before overwrite
    const int gn0 = bn * 128;
#pragma unroll
    for (int u = 0; u < 2; u++) {
        int gnl = wn + u * 16 + r;
        int gng = gn0 + gnl;
        float bv = (gng < HID) ? bias[gng] : 0.0f;
#pragma unroll
        for (int m = 0; m < 2; m++) {
            int gml = wm + m * 16 + quad * 4;
#pragma unroll
            for (int q = 0; q < 4; q++)
                smem[(gml + q) * 136 + gnl] = f2bf(acc[m][u][q] + bv);
        }
    }
    __syncthreads();
    const int row = tid >> 3;            // 128 rows
    const int seg = tid & 7;             // 8 x 16 u16 per row
    const u16* src = smem + row * 136 + seg * 16;
    u16* dst = C + (size_t)(bm * 128 + row) * HIDP + gn0 + seg * 16;
    *(u16x8*)dst       = *(const u16x8*)src;
    *(u16x8*)(dst + 8) = *(const u16x8*)(src + 8);
}

// ---------------- GEMM2: out = g2 @ W2^T + b2 -> fp32 ----------------
// M=11520, K=1984 (ld 2048), N=512.  128x64 tile, BK=64, 512 threads =
// 8 waves (4M x 2N) of 32x32, acc[2][2].  __launch_bounds__(512, 8) ->
// 4 blocks/CU = 32 waves/CU.  2-barrier structure; direct fp32 stores
// (16 lanes x 4B = full 64B lines).
__global__ __launch_bounds__(512, 8) void gemm2_k(const u16* __restrict__ A,
                                                  const u16* __restrict__ B,
                                                  const float* __restrict__ bias,
                                                  float* __restrict__ C) {
    __shared__ u16 sA[128 * 64];         // 16 KB
    __shared__ u16 sB[64 * 64];          //  8 KB

    const int tid  = threadIdx.x;
    const int NB   = gridDim.x;          // 720, %8==0
    const int v    = (blockIdx.x & 7) * (NB >> 3) + (blockIdx.x >> 3);
    const int bm   = v >> 3;             // ntn = 8
    const int bn   = v & 7;
    const int lane = tid & 63;
    const int wv   = tid >> 6;           // 0..7
    const int wm   = (wv >> 1) * 32;
    const int wn   = (wv & 1) * 32;
    const int r    = lane & 15;
    const int quad = lane >> 4;

    const size_t Arow0 = (size_t)bm * 128 * HIDP;
    const size_t Brow0 = (size_t)bn * 64 * HIDP;

    f32x4 acc[2][2] = {};

    for (int kt = 0; kt < KP2; kt += 64) {
        __syncthreads();
#pragma unroll
        for (int i = 0; i < 2; i++) {    // A: 1024 chunks / 512 threads
            int e   = i * 512 + tid;
            int row = e >> 3;
            int cg  = (e & 7) ^ (row & 7);
            gload_lds16(A + Arow0 + (size_t)row * HIDP + kt + cg * 8, (char*)sA + e * 16);
        }
        {                                // B: 512 chunks / 512 threads
            int row = tid >> 3;
            int cg  = (tid & 7) ^ (row & 7);
            gload_lds16(B + Brow0 + (size_t)row * HIDP + kt + cg * 8, (char*)sB + tid * 16);
        }
        __syncthreads();
#pragma unroll
        for (int kk = 0; kk < 2; kk++) {
            bf16x8 af[2], bg[2];
#pragma unroll
            for (int m = 0; m < 2; m++) {
                int row = wm + m * 16 + r;
                int c   = (kk * 4 + quad) ^ (row & 7);
                af[m] = *(const bf16x8*)(sA + row * 64 + c * 8);
            }
#pragma unroll
            for (int u = 0; u < 2; u++) {
                int row = wn + u * 16 + r;
                int c   = (kk * 4 + quad) ^ (row & 7);
                bg[u] = *(const bf16x8*)(sB + row * 64 + c * 8);
            }
#pragma unroll
            for (int m = 0; m < 2; m++)
#pragma unroll
                for (int u = 0; u < 2; u++)
                    acc[m][u] = __builtin_amdgcn_mfma_f32_16x16x32_bf16(
                        af[m], bg[u], acc[m][u], 0, 0, 0);
        }
    }

    const int gm0 = bm * 128 + wm;
    const int gn0 = bn * 64 + wn;
#pragma unroll
    for (int u = 0; u < 2; u++) {
        int gn = gn0 + u * 16 + r;
        float bv = bias[gn];
#pragma unroll
        for (int m = 0; m < 2; m++) {
            int gm = gm0 + m * 16 + quad * 4;
#pragma unroll
            for (int q = 0; q < 4; q++)
                C[(size_t)(gm + q) * DIM + gn] = acc[m][u][q] + bv;
        }
    }
}

// ---------------- mid: fold + normalize + crop + GELU + unfold, fully fused ----------------
// (unchanged; below visibility cutoff since round 1)
__global__ __launch_bounds__(512) void mid_fused(const u16* __restrict__ hg,
                                                 u16* __restrict__ g2) {
    __shared__ u16 sh[12 * 20 * 56];   // 13440 u16 = 26880 B
    __shared__ u16 sG[34 * 58];        //  1972 u16 =  3944 B

    const int b   = blockIdx.x;
    const int bp  = b / (NCH * 4);
    const int rr  = b - bp * (NCH * 4);
    const int ch  = rr >> 2;
    const int s   = (rr >> 1) & 1;
    const int xh  = rr & 1;
    const int o0  = s * 10;            // first owned oy
    const int lo  = s * 8;             // first loaded oy
    const int ox0 = xh * 16;           // first loaded ox
    const int n0  = bp * LVEC;
    const int c0  = ch * 49;
    const int c0f = c0 & ~7;           // 16B-aligned channel base
    const int koff = c0 & 7;           // 0..7 (koff + 49 <= 56)
    const int tid = threadIdx.x;

    // phase 0: 12 oy-rows x 20 ox-cols x 7 chunks of 16B, DMA'd to LDS.
    {
        const char* hb = (const char*)(hg + (size_t)(n0 + lo * 36 + ox0) * HIDP + c0f);
        for (int t = tid; t < 12 * 20 * 7; t += 512) {
            int r   = (int)(((unsigned)t * 74899u) >> 19);
            int c   = t - r * 7;
            int loy = (int)(((unsigned)r * 3277u) >> 16);
            int oxl = r - 20 * loy;
            gload_lds16(hb + (size_t)(loy * 36 + oxl) * (HIDP * 2) + c * 16,
                        (char*)sh + t * 16);
        }
    }
    __syncthreads();

    // phase 1: G rows [3*o0, 3*o0+34) x local px [0,58) -> sG
    const int pxl = tid & 63;
    const int rg  = tid >> 6;          // 0..7, wave-uniform
    if (pxl < 58) {
        const int  pxg  = pxl + 54 * xh;              // global px
        const bool pxin = (pxg >= 3) && (pxg <= 110);
        const int  kx0  = pxg % 3;
        int  ct[3];
        bool vx[3];
        int  cx = 0;
#pragma unroll
        for (int dx = 0; dx < 3; dx++) {
            int kx = kx0 + 3 * dx, rx = pxg - kx;
            bool ok = pxin && (kx <= 6) && (rx >= 0) && (rx <= 105);
            vx[dx] = ok;
            ct[dx] = ok ? ((rx / 3) - ox0) * 56 + kx : 0;
            cx += ok ? 1 : 0;
        }
        const float fcx = (cx == 3) ? (1.0f / 3.0f) : ((cx == 2) ? 0.5f : 1.0f);

        for (int pr = rg; pr < 34; pr += 8) {
            int py = 3 * o0 + pr;      // wave-uniform
            float val = 0.0f;
            if (pxin && py >= 3 && py <= 62) {
                int ky0 = py % 3;
                float sum = 0.0f;
                int cy = 0;
#pragma unroll
                for (int dy = 0; dy < 3; dy++) {
                    int ky = ky0 + 3 * dy, ry = py - ky;   // uniform
                    if (ky <= 6 && ry >= 0 && ry <= 57) {  // uniform branch
                        int rt = (ry / 3 - lo) * (20 * 56) + ky * 7 + koff;
                        cy++;
                        float v0 = bf2f(sh[rt + ct[0]]);
                        float v1 = bf2f(sh[rt + ct[1]]);
                        float v2 = bf2f(sh[rt + ct[2]]);
                        sum += vx[0] ? v0 : 0.0f;
                        sum += vx[1] ? v1 : 0.0f;
                        sum += vx[2] ? v2 : 0.0f;
                    }
                }
                float fcy = (cy == 3) ? (1.0f / 3.0f) : ((cy == 2) ? 0.5f : 1.0f);
                float m = sum * fcx * fcy;
                val = 0.5f * m * (1.0f + erff(m * 0.70710678118654752f));  // exact gelu
            }
            sG[pr * 58 + pxl] = f2bf(val);
        }
    }
    __syncthreads();

    // phase 2: unfold sG -> g2 (magic-mul indices, no LUTs)
    {
        u16* g2row = g2 + (size_t)(n0 + o0 * 36 + 18 * xh) * HIDP + c0;
        for (int j = tid; j < 10 * 18 * 49; j += 512) {
            int l2 = (int)(((unsigned)j * 42800u) >> 21);
            int k  = j - l2 * 49;
            int oy = (int)(((unsigned)l2 * 57u) >> 10);
            int ox = l2 - 18 * oy;
            int ky = (int)(((unsigned)k * 37u) >> 8);
            int kx = k - 7 * ky;
            g2row[(size_t)(oy * 36 + ox) * HIDP + k] =
                sG[(3 * oy + ky) * 58 + 3 * ox + kx];
        }
    }
}

// ---------------- launch ----------------
extern "C" void kernel_launch(void* const* d_in, const int* in_sizes, int n_in,
                              void* d_out, int out_size, void* d_ws, size_t ws_size,
                              hipStream_t stream) {
    (void)in_sizes; (void)n_in; (void)out_size; (void)ws_size;
    const float* x  = (const float*)d_in[0];
    const float* W1 = (const float*)d_in[1];
    const float* b1 = (const float*)d_in[2];
    const float* W2 = (const float*)d_in[3];
    const float* b2 = (const float*)d_in[4];
    float* out = (float*)d_out;

    char* ws = (char*)d_ws;
    u16* xb  = (u16*)(ws);                       // 11520*512*2  = 11,796,480
    u16* W1b = (u16*)(ws + 11796480);            // 2048*512*2   =  2,097,152
    u16* W2b = (u16*)(ws + 13893632);            // 512*2048*2   =  2,097,152
    u16* hg  = (u16*)(ws + 15990784);            // 11520*2048*2 = 47,185,920
    u16* g2  = (u16*)(ws + 63176704);            // 11520*2048*2 = 47,185,920 (total 110 MB)

    // converts + g2 pad-zeroing (single dispatch)
    cvt_all<<<CVT_XB + CVT_W1B + CVT_W2B + CVT_Z, 256, 0, stream>>>(
        x, W1, W2, xb, W1b, W2b, g2);

    // GEMM1: 128x128 tiles, 1024 threads (16 waves of 32x32), grid 90*16=1440
    gemm1_k<<<(M_ROWS / 128) * (HIDP / 128), 1024, 0, stream>>>(xb, W1b, b1, hg);

    // middle: fold/normalize/gelu/unfold fused, hg -> g2 (G stays in LDS)
    mid_fused<<<BPRIME * NCH * 4, 512, 0, stream>>>(hg, g2);

    // GEMM2: 128x64 tiles, 512 threads (8 waves of 32x32), grid 90*8=720
    gemm2_k<<<(M_ROWS / 128) * (DIM / 64), 512, 0, stream>>>(g2, W2b, b2, out);
}